// Round 20
// baseline (66.725 us; speedup 1.0000x reference)
//
#include <hip/hip_runtime.h>
#include <hip/hip_bf16.h>
#include <math.h>

// ---------------------------------------------------------------------------
// ColorizationNet inference, 3 kernels:
//  1) fused_conv_prep_k: conv1..pool3 fully fused per 2x2 tile (r14: -35us)
//  2) base_acc_k: flat-segment split-K (float4-aligned w1 stream, r19)
//  3) chunk_k: per-chunk MLP, CPB=4 @1024 blocks. h2 mapping: thread =
//     1 chunk x 4 outputs STRIDED BY 44 — keeps weight coalescing
//     (consecutive lanes -> consecutive float4s) AND cuts ds_read_b128
//     per thread 304 -> 76 (LDS pipe was the modeled h2 bottleneck).
//     All other mappings tried (r5/6/9/10/15/16/17/18) broke TLP, spilled,
//     or broke coalescing; this one preserves every proven invariant.
// ---------------------------------------------------------------------------

#define CONV_FLAT 32768
#define H1_  304
#define H2_  176
#define OUT_ 48
#define CPB  4
#define W1ROW 32786
#define TOTF (304u * 32786u)
#define BSEG 2048
#define NSEGB ((TOTF + BSEG - 1) / BSEG)   // 4867

// ws layout (float offsets)
#define WS_XC    196608
#define WS_BASE  229376
#define WS_W1PCT 229696
#define WS_W2Q   235168
#define WS_W3Q   288672

// ---------------- fused conv backbone (+ weight prep tail) ------------------
__global__ __launch_bounds__(256)
void fused_conv_prep_k(const float* __restrict__ x,
                       const float* __restrict__ c1w, const float* __restrict__ c1b,
                       const float* __restrict__ c2w, const float* __restrict__ c2b,
                       const float* __restrict__ c3w, const float* __restrict__ c3b,
                       const float* __restrict__ w1, const float* __restrict__ w2,
                       const float* __restrict__ w3, const float* __restrict__ b1,
                       float* __restrict__ xconv, float* __restrict__ w1pcT,
                       float* __restrict__ w2q, float* __restrict__ w3q,
                       float* __restrict__ base) {
    int tid = threadIdx.x;
    if (blockIdx.x >= 256) {        // ---- prep tail (209 blocks) ----
        int idx = (blockIdx.x - 256) * 256 + tid;
        if (idx < 304 * 176) {                     // w2 row-major [176][304]
            int t = idx / 304, k = idx - t * 304;
            w2q[(k >> 2) * (H2_ * 4) + t * 4 + (k & 3)] = w2[idx];
        }
        if (idx < 48 * 176) {                      // w3 row-major [48][176]
            int t = idx / 176, k = idx - t * 176;
            w3q[(k >> 2) * 192 + t * 4 + (k & 3)] = w3[idx];
        }
        if (idx < 304 * 18) {                      // w1[:, 32768+k]
            int t = idx / 18, k = idx - t * 18;
            w1pcT[k * 304 + t] = w1[(size_t)t * W1ROW + 32768 + k];
        }
        if (idx < H1_) base[idx] = b1[idx];
        return;
    }
    int ti = blockIdx.x >> 4, tj = blockIdx.x & 15;

    __shared__ float xl[30][30];
    __shared__ float c1l[8][14][14];
    __shared__ float c2l[16][6][6];

    for (int e = tid; e < 900; e += 256) {
        int a = e / 30, b = e - a * 30;
        int gy = 16 * ti - 7 + a, gx = 16 * tj - 7 + b;
        float v = 0.f;
        if ((unsigned)gy < 256u && (unsigned)gx < 256u) v = x[gy * 256 + gx];
        xl[a][b] = v;
    }
    __syncthreads();

    for (int e = tid; e < 1568; e += 256) {
        int c = e / 196, r = e - c * 196;
        int a = r / 14, b = r - a * 14;
        int gv = 8 * ti - 3 + a, gu = 8 * tj - 3 + b;
        float val = 0.f;
        if ((unsigned)gv < 128u && (unsigned)gu < 128u) {
            const float* wp = c1w + c * 9;
            float bias = c1b[c];
            float s00 = bias, s01 = bias, s10 = bias, s11 = bias;
#pragma unroll
            for (int ky = 0; ky < 3; ky++) {
#pragma unroll
                for (int kx = 0; kx < 3; kx++) {
                    float wv = wp[ky * 3 + kx];
                    s00 += xl[2 * a + 0 + ky][2 * b + 0 + kx] * wv;
                    s01 += xl[2 * a + 0 + ky][2 * b + 1 + kx] * wv;
                    s10 += xl[2 * a + 1 + ky][2 * b + 0 + kx] * wv;
                    s11 += xl[2 * a + 1 + ky][2 * b + 1 + kx] * wv;
                }
            }
            val = fmaxf(fmaxf(fmaxf(s00, s01), fmaxf(s10, s11)), 0.f);
        }
        c1l[c][a][b] = val;
    }
    __syncthreads();

    for (int e = tid; e < 576; e += 256) {
        int c = e / 36, r = e - c * 36;
        int a = r / 6, b = r - a * 6;
        int gsy = 4 * ti - 1 + a, gsx = 4 * tj - 1 + b;
        float val = 0.f;
        if ((unsigned)gsy < 64u && (unsigned)gsx < 64u) {
            float bias = c2b[c];
            float s00 = bias, s01 = bias, s10 = bias, s11 = bias;
            const float* wb = c2w + c * 72;
#pragma unroll
            for (int ic = 0; ic < 8; ic++) {
                const float* wp = wb + ic * 9;
#pragma unroll
                for (int ky = 0; ky < 3; ky++) {
#pragma unroll
                    for (int kx = 0; kx < 3; kx++) {
                        float wv = wp[ky * 3 + kx];
                        s00 += c1l[ic][2 * a + 0 + ky][2 * b + 0 + kx] * wv;
                        s01 += c1l[ic][2 * a + 0 + ky][2 * b + 1 + kx] * wv;
                        s10 += c1l[ic][2 * a + 1 + ky][2 * b + 0 + kx] * wv;
                        s11 += c1l[ic][2 * a + 1 + ky][2 * b + 1 + kx] * wv;
                    }
                }
            }
            val = fmaxf(fmaxf(fmaxf(s00, s01), fmaxf(s10, s11)), 0.f);
        }
        c2l[c][a][b] = val;
    }
    __syncthreads();

    if (tid < 128) {
        int oc = tid >> 2, ql = tid & 3;
        int qly = ql >> 1, qlx = ql & 1;
        float bias = c3b[oc];
        float s00 = bias, s01 = bias, s10 = bias, s11 = bias;
        const float* wb = c3w + oc * 144;
#pragma unroll
        for (int ic = 0; ic < 16; ic++) {
            const float* wp = wb + ic * 9;
#pragma unroll
            for (int ky = 0; ky < 3; ky++) {
#pragma unroll
                for (int kx = 0; kx < 3; kx++) {
                    float wv = wp[ky * 3 + kx];
                    s00 += c2l[ic][2 * qly + 0 + ky][2 * qlx + 0 + kx] * wv;
                    s01 += c2l[ic][2 * qly + 0 + ky][2 * qlx + 1 + kx] * wv;
                    s10 += c2l[ic][2 * qly + 1 + ky][2 * qlx + 0 + kx] * wv;
                    s11 += c2l[ic][2 * qly + 1 + ky][2 * qlx + 1 + kx] * wv;
                }
            }
        }
        float val = fmaxf(fmaxf(fmaxf(s00, s01), fmaxf(s10, s11)), 0.f);
        xconv[oc * 1024 + (2 * ti + qly) * 32 + (2 * tj + qlx)] = val;
    }
}

// flat-segment split-K over w1 (r19; neutral vs NSEG16 but aligned-stream)
__global__ void base_acc_k(const float* __restrict__ w1, const float* __restrict__ xconv,
                           float* __restrict__ base) {
    const size_t s0 = (size_t)blockIdx.x * BSEG;
    const int tid = threadIdx.x;
    int rowA = (int)(s0 / W1ROW);
    size_t rsA = (size_t)rowA * W1ROW;
    float accA = 0.f, accB = 0.f;
    bool fast = (s0 + BSEG <= rsA + 32768);
    if (fast) {
        int col0 = (int)(s0 - rsA);
        const float4* wp = (const float4*)(w1 + s0);
        const float2* xp = (const float2*)(xconv + col0);
#pragma unroll
        for (int p = 0; p < 2; p++) {
            int q = tid + p * 256;
            float4 a = wp[q];
            float2 v0 = xp[q * 2], v1 = xp[q * 2 + 1];
            accA += a.x * v0.x + a.y * v0.y + a.z * v1.x + a.w * v1.y;
        }
    } else {
#pragma unroll
        for (int p = 0; p < 2; p++) {
            size_t f = s0 + (size_t)(tid + p * 256) * 4;
#pragma unroll
            for (int e = 0; e < 4; e++) {
                size_t fe = f + e;
                if (fe < (size_t)TOTF) {
                    int r = (int)(fe / W1ROW);
                    int c = (int)(fe - (size_t)r * W1ROW);
                    if (c < 32768) {
                        float t = w1[fe] * xconv[c];
                        if (r == rowA) accA += t; else accB += t;
                    }
                }
            }
        }
    }
#pragma unroll
    for (int off = 32; off > 0; off >>= 1) {
        accA += __shfl_down(accA, off, 64);
        accB += __shfl_down(accB, off, 64);
    }
    __shared__ float redA[4], redB[4];
    int lane = tid & 63, wid = tid >> 6;
    if (lane == 0) { redA[wid] = accA; redB[wid] = accB; }
    __syncthreads();
    if (tid == 0) {
        atomicAdd(&base[rowA], redA[0] + redA[1] + redA[2] + redA[3]);
        float sB = redB[0] + redB[1] + redB[2] + redB[3];
        if (!fast && rowA + 1 < H1_ && sB != 0.f)
            atomicAdd(&base[rowA + 1], sB);
    }
}

// fused per-chunk MLP, 4 chunks/block, 1024 blocks.
// h2: thread = 1 chunk (tid/44) x 4 outputs strided by 44 (tid%44 + j*44).
__global__ void chunk_k(const float* __restrict__ x, const float* __restrict__ base,
                        const float* __restrict__ w1pcT, const float* __restrict__ w2q,
                        const float* __restrict__ b2, const float* __restrict__ w3q,
                        const float* __restrict__ b3, float* __restrict__ out) {
    __shared__ float pc[CPB][18];
    __shared__ float h1[CPB][H1_];
    __shared__ float h2s[CPB][H2_];
    int tid = threadIdx.x;
    int c0 = blockIdx.x * CPB;

    if (tid < CPB * 18) {
        int u = tid / 18, k = tid - u * 18;
        int c = c0 + u;
        int i = c >> 6, j = c & 63;
        float v;
        if (k == 0)      v = (float)(i * 4);
        else if (k == 1) v = (float)(j * 4);
        else {
            int kk = k - 2;
            int r = kk >> 2, cc = kk & 3;
            v = x[(i * 4 + r) * 256 + j * 4 + cc];
        }
        pc[u][k] = v;
    }
    __syncthreads();

    // h1: 304 outputs x 4 chunks
    for (int t = tid; t < H1_; t += 256) {
        float bb = base[t];
        float acc[CPB];
#pragma unroll
        for (int u = 0; u < CPB; u++) acc[u] = bb;
#pragma unroll
        for (int k = 0; k < 18; k++) {
            float w = w1pcT[k * H1_ + t];
#pragma unroll
            for (int u = 0; u < CPB; u++) acc[u] += w * pc[u][k];
        }
#pragma unroll
        for (int u = 0; u < CPB; u++) h1[u][t] = fmaxf(acc[u], 0.f);
    }
    __syncthreads();

    // h2: thread = chunk u x outputs {tg, tg+44, tg+88, tg+132}
    if (tid < 176) {
        int u = tid / 44, tg = tid - u * 44;
        const float4* wq = (const float4*)w2q;   // [76][176] float4s
        float a0 = b2[tg +   0];
        float a1 = b2[tg +  44];
        float a2 = b2[tg +  88];
        float a3 = b2[tg + 132];
#pragma unroll 4
        for (int g = 0; g < 76; g++) {
            float4 h = *(const float4*)&h1[u][g * 4];   // 1 ds_read, 2-way bcast
            float4 w0  = wq[g * H2_ + tg +   0];        // coalesced (44 lanes)
            float4 w1v = wq[g * H2_ + tg +  44];
            float4 w2v = wq[g * H2_ + tg +  88];
            float4 w3v = wq[g * H2_ + tg + 132];
            a0 += w0.x  * h.x + w0.y  * h.y + w0.z  * h.z + w0.w  * h.w;
            a1 += w1v.x * h.x + w1v.y * h.y + w1v.z * h.z + w1v.w * h.w;
            a2 += w2v.x * h.x + w2v.y * h.y + w2v.z * h.z + w2v.w * h.w;
            a3 += w3v.x * h.x + w3v.y * h.y + w3v.z * h.z + w3v.w * h.w;
        }
        h2s[u][tg +   0] = fmaxf(a0, 0.f);
        h2s[u][tg +  44] = fmaxf(a1, 0.f);
        h2s[u][tg +  88] = fmaxf(a2, 0.f);
        h2s[u][tg + 132] = fmaxf(a3, 0.f);
    }
    __syncthreads();

    // out: 48 outputs x 4 chunks = 192 threads
    if (tid < CPB * OUT_) {
        int u = tid / OUT_, t = tid - u * OUT_;
        const float4* wq = (const float4*)w3q;   // [44][48] float4s
        float acc = b3[t];
#pragma unroll 4
        for (int g = 0; g < 44; g++) {
            float4 w = wq[g * OUT_ + t];
            float4 h = *(const float4*)&h2s[u][g * 4];
            acc += w.x * h.x + w.y * h.y + w.z * h.z + w.w * h.w;
        }
        out[(size_t)(c0 + u) * OUT_ + t] = 1.f / (1.f + expf(-acc));
    }
}

extern "C" void kernel_launch(void* const* d_in, const int* in_sizes, int n_in,
                              void* d_out, int out_size, void* d_ws, size_t ws_size,
                              hipStream_t stream) {
    const float* x    = (const float*)d_in[0];
    const float* c1_w = (const float*)d_in[1];
    const float* c1_b = (const float*)d_in[2];
    const float* c2_w = (const float*)d_in[3];
    const float* c2_b = (const float*)d_in[4];
    const float* c3_w = (const float*)d_in[5];
    const float* c3_b = (const float*)d_in[6];
    const float* w1   = (const float*)d_in[7];
    const float* b1   = (const float*)d_in[8];
    const float* w2   = (const float*)d_in[9];
    const float* b2   = (const float*)d_in[10];
    const float* w3   = (const float*)d_in[11];
    const float* b3   = (const float*)d_in[12];
    float* out = (float*)d_out;
    float* ws  = (float*)d_ws;

    float* xconv  = ws + WS_XC;
    float* base   = ws + WS_BASE;
    float* w1pcT  = ws + WS_W1PCT;
    float* w2q    = ws + WS_W2Q;
    float* w3q    = ws + WS_W3Q;

    fused_conv_prep_k<<<256 + 209, 256, 0, stream>>>(
        x, c1_w, c1_b, c2_w, c2_b, c3_w, c3_b, w1, w2, w3, b1,
        xconv, w1pcT, w2q, w3q, base);
    base_acc_k<<<NSEGB, 256, 0, stream>>>(w1, xconv, base);
    chunk_k<<<1024, 256, 0, stream>>>(x, base, w1pcT, w2q, b2, w3q, b3, out);
}

// Round 21
// 59.458 us; speedup vs baseline: 1.1222x; 1.1222x over previous
//
#include <hip/hip_runtime.h>
#include <hip/hip_bf16.h>
#include <math.h>

// ---------------------------------------------------------------------------
// ColorizationNet inference, 3 kernels:
//  1) fused_conv_prep_k: conv1..pool3 fully fused per 2x2 tile (r14: -35us)
//  2) base_acc_k: flat-segment split-K (float4-aligned w1 stream, r19)
//  3) chunk_k: per-chunk MLP, CPB=4 @1024 blocks, r3-proven mapping
//     (weights once/block coalesced, h1 broadcast) with BOTH h2 streams in
//     bf16: w2 packed 8-k/uint4, h1 stored bf16 in LDS. Halves LDS instrs
//     (304->152/thread) and weight loads (76->38) at +1 VALU/value unpack.
//     9 mapping restructures all lost to this form; format is the lever.
// ---------------------------------------------------------------------------

#define CONV_FLAT 32768
#define H1_  304
#define H2_  176
#define OUT_ 48
#define CPB  4
#define W1ROW 32786
#define TOTF (304u * 32786u)
#define BSEG 2048
#define NSEGB ((TOTF + BSEG - 1) / BSEG)   // 4867

// ws layout (float offsets)
#define WS_XC    196608
#define WS_BASE  229376
#define WS_W1PCT 229696
#define WS_W2B   235168     // 38*176 uint4 = 26752 floats (bf16-packed w2)
#define WS_W3Q   288672     // 44*48*4 = 8448

__device__ __forceinline__ float bflo(unsigned v) { return __uint_as_float(v << 16); }
__device__ __forceinline__ float bfhi(unsigned v) { return __uint_as_float(v & 0xffff0000u); }
__device__ __forceinline__ unsigned short f2bf(float f) {
    unsigned u = __float_as_uint(f);
    unsigned r = (u + 0x7fffu + ((u >> 16) & 1)) >> 16;   // RNE
    return (unsigned short)r;
}

// ---------------- fused conv backbone (+ weight prep tail) ------------------
__global__ __launch_bounds__(256)
void fused_conv_prep_k(const float* __restrict__ x,
                       const float* __restrict__ c1w, const float* __restrict__ c1b,
                       const float* __restrict__ c2w, const float* __restrict__ c2b,
                       const float* __restrict__ c3w, const float* __restrict__ c3b,
                       const float* __restrict__ w1, const float* __restrict__ w2,
                       const float* __restrict__ w3, const float* __restrict__ b1,
                       float* __restrict__ xconv, float* __restrict__ w1pcT,
                       unsigned short* __restrict__ w2b, float* __restrict__ w3q,
                       float* __restrict__ base) {
    int tid = threadIdx.x;
    if (blockIdx.x >= 256) {        // ---- prep tail (209 blocks) ----
        int idx = (blockIdx.x - 256) * 256 + tid;
        if (idx < 304 * 176) {                     // w2 row-major [176][304]
            int t = idx / 304, k = idx - t * 304;
            int gg = k >> 3, e = k & 7;
            w2b[((size_t)gg * H2_ + t) * 8 + e] = f2bf(w2[idx]);
        }
        if (idx < 48 * 176) {                      // w3 row-major [48][176]
            int t = idx / 176, k = idx - t * 176;
            w3q[(k >> 2) * 192 + t * 4 + (k & 3)] = w3[idx];
        }
        if (idx < 304 * 18) {                      // w1[:, 32768+k]
            int t = idx / 18, k = idx - t * 18;
            w1pcT[k * 304 + t] = w1[(size_t)t * W1ROW + 32768 + k];
        }
        if (idx < H1_) base[idx] = b1[idx];
        return;
    }
    int ti = blockIdx.x >> 4, tj = blockIdx.x & 15;

    __shared__ float xl[30][30];
    __shared__ float c1l[8][14][14];
    __shared__ float c2l[16][6][6];

    for (int e = tid; e < 900; e += 256) {
        int a = e / 30, b = e - a * 30;
        int gy = 16 * ti - 7 + a, gx = 16 * tj - 7 + b;
        float v = 0.f;
        if ((unsigned)gy < 256u && (unsigned)gx < 256u) v = x[gy * 256 + gx];
        xl[a][b] = v;
    }
    __syncthreads();

    for (int e = tid; e < 1568; e += 256) {
        int c = e / 196, r = e - c * 196;
        int a = r / 14, b = r - a * 14;
        int gv = 8 * ti - 3 + a, gu = 8 * tj - 3 + b;
        float val = 0.f;
        if ((unsigned)gv < 128u && (unsigned)gu < 128u) {
            const float* wp = c1w + c * 9;
            float bias = c1b[c];
            float s00 = bias, s01 = bias, s10 = bias, s11 = bias;
#pragma unroll
            for (int ky = 0; ky < 3; ky++) {
#pragma unroll
                for (int kx = 0; kx < 3; kx++) {
                    float wv = wp[ky * 3 + kx];
                    s00 += xl[2 * a + 0 + ky][2 * b + 0 + kx] * wv;
                    s01 += xl[2 * a + 0 + ky][2 * b + 1 + kx] * wv;
                    s10 += xl[2 * a + 1 + ky][2 * b + 0 + kx] * wv;
                    s11 += xl[2 * a + 1 + ky][2 * b + 1 + kx] * wv;
                }
            }
            val = fmaxf(fmaxf(fmaxf(s00, s01), fmaxf(s10, s11)), 0.f);
        }
        c1l[c][a][b] = val;
    }
    __syncthreads();

    for (int e = tid; e < 576; e += 256) {
        int c = e / 36, r = e - c * 36;
        int a = r / 6, b = r - a * 6;
        int gsy = 4 * ti - 1 + a, gsx = 4 * tj - 1 + b;
        float val = 0.f;
        if ((unsigned)gsy < 64u && (unsigned)gsx < 64u) {
            float bias = c2b[c];
            float s00 = bias, s01 = bias, s10 = bias, s11 = bias;
            const float* wb = c2w + c * 72;
#pragma unroll
            for (int ic = 0; ic < 8; ic++) {
                const float* wp = wb + ic * 9;
#pragma unroll
                for (int ky = 0; ky < 3; ky++) {
#pragma unroll
                    for (int kx = 0; kx < 3; kx++) {
                        float wv = wp[ky * 3 + kx];
                        s00 += c1l[ic][2 * a + 0 + ky][2 * b + 0 + kx] * wv;
                        s01 += c1l[ic][2 * a + 0 + ky][2 * b + 1 + kx] * wv;
                        s10 += c1l[ic][2 * a + 1 + ky][2 * b + 0 + kx] * wv;
                        s11 += c1l[ic][2 * a + 1 + ky][2 * b + 1 + kx] * wv;
                    }
                }
            }
            val = fmaxf(fmaxf(fmaxf(s00, s01), fmaxf(s10, s11)), 0.f);
        }
        c2l[c][a][b] = val;
    }
    __syncthreads();

    if (tid < 128) {
        int oc = tid >> 2, ql = tid & 3;
        int qly = ql >> 1, qlx = ql & 1;
        float bias = c3b[oc];
        float s00 = bias, s01 = bias, s10 = bias, s11 = bias;
        const float* wb = c3w + oc * 144;
#pragma unroll
        for (int ic = 0; ic < 16; ic++) {
            const float* wp = wb + ic * 9;
#pragma unroll
            for (int ky = 0; ky < 3; ky++) {
#pragma unroll
                for (int kx = 0; kx < 3; kx++) {
                    float wv = wp[ky * 3 + kx];
                    s00 += c2l[ic][2 * qly + 0 + ky][2 * qlx + 0 + kx] * wv;
                    s01 += c2l[ic][2 * qly + 0 + ky][2 * qlx + 1 + kx] * wv;
                    s10 += c2l[ic][2 * qly + 1 + ky][2 * qlx + 0 + kx] * wv;
                    s11 += c2l[ic][2 * qly + 1 + ky][2 * qlx + 1 + kx] * wv;
                }
            }
        }
        float val = fmaxf(fmaxf(fmaxf(s00, s01), fmaxf(s10, s11)), 0.f);
        xconv[oc * 1024 + (2 * ti + qly) * 32 + (2 * tj + qlx)] = val;
    }
}

// flat-segment split-K over w1 (r19)
__global__ void base_acc_k(const float* __restrict__ w1, const float* __restrict__ xconv,
                           float* __restrict__ base) {
    const size_t s0 = (size_t)blockIdx.x * BSEG;
    const int tid = threadIdx.x;
    int rowA = (int)(s0 / W1ROW);
    size_t rsA = (size_t)rowA * W1ROW;
    float accA = 0.f, accB = 0.f;
    bool fast = (s0 + BSEG <= rsA + 32768);
    if (fast) {
        int col0 = (int)(s0 - rsA);
        const float4* wp = (const float4*)(w1 + s0);
        const float2* xp = (const float2*)(xconv + col0);
#pragma unroll
        for (int p = 0; p < 2; p++) {
            int q = tid + p * 256;
            float4 a = wp[q];
            float2 v0 = xp[q * 2], v1 = xp[q * 2 + 1];
            accA += a.x * v0.x + a.y * v0.y + a.z * v1.x + a.w * v1.y;
        }
    } else {
#pragma unroll
        for (int p = 0; p < 2; p++) {
            size_t f = s0 + (size_t)(tid + p * 256) * 4;
#pragma unroll
            for (int e = 0; e < 4; e++) {
                size_t fe = f + e;
                if (fe < (size_t)TOTF) {
                    int r = (int)(fe / W1ROW);
                    int c = (int)(fe - (size_t)r * W1ROW);
                    if (c < 32768) {
                        float t = w1[fe] * xconv[c];
                        if (r == rowA) accA += t; else accB += t;
                    }
                }
            }
        }
    }
#pragma unroll
    for (int off = 32; off > 0; off >>= 1) {
        accA += __shfl_down(accA, off, 64);
        accB += __shfl_down(accB, off, 64);
    }
    __shared__ float redA[4], redB[4];
    int lane = tid & 63, wid = tid >> 6;
    if (lane == 0) { redA[wid] = accA; redB[wid] = accB; }
    __syncthreads();
    if (tid == 0) {
        atomicAdd(&base[rowA], redA[0] + redA[1] + redA[2] + redA[3]);
        float sB = redB[0] + redB[1] + redB[2] + redB[3];
        if (!fast && rowA + 1 < H1_ && sB != 0.f)
            atomicAdd(&base[rowA + 1], sB);
    }
}

// fused per-chunk MLP, 4 chunks/block, 1024 blocks; h2 streams in bf16.
__global__ void chunk_k(const float* __restrict__ x, const float* __restrict__ base,
                        const float* __restrict__ w1pcT,
                        const unsigned short* __restrict__ w2b,
                        const float* __restrict__ b2, const float* __restrict__ w3q,
                        const float* __restrict__ b3, float* __restrict__ out) {
    __shared__ float pc[CPB][18];
    __shared__ unsigned short h1s[CPB][H1_];   // bf16; rows 608B = 38*16B
    __shared__ float h2s[CPB][H2_];
    int tid = threadIdx.x;
    int c0 = blockIdx.x * CPB;

    if (tid < CPB * 18) {
        int u = tid / 18, k = tid - u * 18;
        int c = c0 + u;
        int i = c >> 6, j = c & 63;
        float v;
        if (k == 0)      v = (float)(i * 4);
        else if (k == 1) v = (float)(j * 4);
        else {
            int kk = k - 2;
            int r = kk >> 2, cc = kk & 3;
            v = x[(i * 4 + r) * 256 + j * 4 + cc];
        }
        pc[u][k] = v;
    }
    __syncthreads();

    // h1: 304 outputs x 4 chunks -> bf16 LDS
    for (int t = tid; t < H1_; t += 256) {
        float bb = base[t];
        float acc[CPB];
#pragma unroll
        for (int u = 0; u < CPB; u++) acc[u] = bb;
#pragma unroll
        for (int k = 0; k < 18; k++) {
            float w = w1pcT[k * H1_ + t];
#pragma unroll
            for (int u = 0; u < CPB; u++) acc[u] += w * pc[u][k];
        }
#pragma unroll
        for (int u = 0; u < CPB; u++) h1s[u][t] = f2bf(fmaxf(acc[u], 0.f));
    }
    __syncthreads();

    // h2: 176 outputs x 4 chunks; per gg (8 k): 1 coalesced uint4 weight load
    // + 4 broadcast uint4 LDS reads; unpack bf16 pairs via AND/SHL.
    if (tid < H2_) {
        const uint4* wb = (const uint4*)w2b;    // [38][176]
        float acc[CPB];
#pragma unroll
        for (int u = 0; u < CPB; u++) acc[u] = b2[tid];
#pragma unroll 2
        for (int gg = 0; gg < 38; gg++) {
            uint4 wv = wb[gg * H2_ + tid];
            float w0 = bflo(wv.x), w1f = bfhi(wv.x);
            float w2f = bflo(wv.y), w3f = bfhi(wv.y);
            float w4 = bflo(wv.z), w5 = bfhi(wv.z);
            float w6 = bflo(wv.w), w7 = bfhi(wv.w);
#pragma unroll
            for (int u = 0; u < CPB; u++) {
                uint4 hv = *(const uint4*)&h1s[u][gg * 8];
                acc[u] += w0 * bflo(hv.x) + w1f * bfhi(hv.x)
                        + w2f * bflo(hv.y) + w3f * bfhi(hv.y)
                        + w4 * bflo(hv.z) + w5 * bfhi(hv.z)
                        + w6 * bflo(hv.w) + w7 * bfhi(hv.w);
            }
        }
#pragma unroll
        for (int u = 0; u < CPB; u++) h2s[u][tid] = fmaxf(acc[u], 0.f);
    }
    __syncthreads();

    // out: 48 outputs x 4 chunks = 192 threads (fp32, unchanged)
    if (tid < CPB * OUT_) {
        int u = tid / OUT_, t = tid - u * OUT_;
        const float4* wq = (const float4*)w3q;   // [44][48]
        float acc = b3[t];
#pragma unroll 4
        for (int g = 0; g < 44; g++) {
            float4 w = wq[g * OUT_ + t];
            float4 h = *(const float4*)&h2s[u][g * 4];
            acc += w.x * h.x + w.y * h.y + w.z * h.z + w.w * h.w;
        }
        out[(size_t)(c0 + u) * OUT_ + t] = 1.f / (1.f + expf(-acc));
    }
}

extern "C" void kernel_launch(void* const* d_in, const int* in_sizes, int n_in,
                              void* d_out, int out_size, void* d_ws, size_t ws_size,
                              hipStream_t stream) {
    const float* x    = (const float*)d_in[0];
    const float* c1_w = (const float*)d_in[1];
    const float* c1_b = (const float*)d_in[2];
    const float* c2_w = (const float*)d_in[3];
    const float* c2_b = (const float*)d_in[4];
    const float* c3_w = (const float*)d_in[5];
    const float* c3_b = (const float*)d_in[6];
    const float* w1   = (const float*)d_in[7];
    const float* b1   = (const float*)d_in[8];
    const float* w2   = (const float*)d_in[9];
    const float* b2   = (const float*)d_in[10];
    const float* w3   = (const float*)d_in[11];
    const float* b3   = (const float*)d_in[12];
    float* out = (float*)d_out;
    float* ws  = (float*)d_ws;

    float* xconv  = ws + WS_XC;
    float* base   = ws + WS_BASE;
    float* w1pcT  = ws + WS_W1PCT;
    unsigned short* w2b = (unsigned short*)(ws + WS_W2B);
    float* w3q    = ws + WS_W3Q;

    fused_conv_prep_k<<<256 + 209, 256, 0, stream>>>(
        x, c1_w, c1_b, c2_w, c2_b, c3_w, c3_b, w1, w2, w3, b1,
        xconv, w1pcT, w2b, w3q, base);
    base_acc_k<<<NSEGB, 256, 0, stream>>>(w1, xconv, base);
    chunk_k<<<1024, 256, 0, stream>>>(x, base, w1pcT, w2b, b2, w3q, b3, out);
}

// Round 22
// 54.839 us; speedup vs baseline: 1.2167x; 1.0842x over previous
//
#include <hip/hip_runtime.h>
#include <hip/hip_bf16.h>
#include <math.h>

// ---------------------------------------------------------------------------
// ColorizationNet inference, 3 kernels (r19 structure + non-temporal staging):
//  1) fused_conv_prep_k: conv1..pool3 fully fused per 2x2 tile (r14: -35us).
//     ALL cross-kernel staging writes (xconv, w1pcT, w2q, w3q, base) use
//     __builtin_nontemporal_store so no dirty L2 lines are left in the
//     writer's XCD — consumers on other XCDs read clean L3/L2-cacheable
//     lines (r13's conv-staging overfetch mechanism, applied to weights:
//     r16 chunk FETCH was 17.8MB for ~2MB of resident data).
//  2) base_acc_k: flat-segment split-K (float4-aligned w1 stream, r19)
//  3) chunk_k: per-chunk MLP, CPB=4 @1024 blocks, r3-proven mapping (fp32) —
//     ten restructures (r5..r21) all lost to or tied this form.
// ---------------------------------------------------------------------------

#define CONV_FLAT 32768
#define H1_  304
#define H2_  176
#define OUT_ 48
#define CPB  4
#define W1ROW 32786
#define TOTF (304u * 32786u)
#define BSEG 2048
#define NSEGB ((TOTF + BSEG - 1) / BSEG)   // 4867

// ws layout (float offsets)
#define WS_XC    196608
#define WS_BASE  229376
#define WS_W1PCT 229696
#define WS_W2Q   235168
#define WS_W3Q   288672

#define NTS(p, v) __builtin_nontemporal_store((v), (p))

// ---------------- fused conv backbone (+ weight prep tail) ------------------
__global__ __launch_bounds__(256)
void fused_conv_prep_k(const float* __restrict__ x,
                       const float* __restrict__ c1w, const float* __restrict__ c1b,
                       const float* __restrict__ c2w, const float* __restrict__ c2b,
                       const float* __restrict__ c3w, const float* __restrict__ c3b,
                       const float* __restrict__ w1, const float* __restrict__ w2,
                       const float* __restrict__ w3, const float* __restrict__ b1,
                       float* __restrict__ xconv, float* __restrict__ w1pcT,
                       float* __restrict__ w2q, float* __restrict__ w3q,
                       float* __restrict__ base) {
    int tid = threadIdx.x;
    if (blockIdx.x >= 256) {        // ---- prep tail (209 blocks) ----
        int idx = (blockIdx.x - 256) * 256 + tid;
        if (idx < 304 * 176) {                     // w2 row-major [176][304]
            int t = idx / 304, k = idx - t * 304;
            NTS(&w2q[(k >> 2) * (H2_ * 4) + t * 4 + (k & 3)], w2[idx]);
        }
        if (idx < 48 * 176) {                      // w3 row-major [48][176]
            int t = idx / 176, k = idx - t * 176;
            NTS(&w3q[(k >> 2) * 192 + t * 4 + (k & 3)], w3[idx]);
        }
        if (idx < 304 * 18) {                      // w1[:, 32768+k]
            int t = idx / 18, k = idx - t * 18;
            NTS(&w1pcT[k * 304 + t], w1[(size_t)t * W1ROW + 32768 + k]);
        }
        if (idx < H1_) NTS(&base[idx], b1[idx]);
        return;
    }
    int ti = blockIdx.x >> 4, tj = blockIdx.x & 15;

    __shared__ float xl[30][30];
    __shared__ float c1l[8][14][14];
    __shared__ float c2l[16][6][6];

    for (int e = tid; e < 900; e += 256) {
        int a = e / 30, b = e - a * 30;
        int gy = 16 * ti - 7 + a, gx = 16 * tj - 7 + b;
        float v = 0.f;
        if ((unsigned)gy < 256u && (unsigned)gx < 256u) v = x[gy * 256 + gx];
        xl[a][b] = v;
    }
    __syncthreads();

    for (int e = tid; e < 1568; e += 256) {
        int c = e / 196, r = e - c * 196;
        int a = r / 14, b = r - a * 14;
        int gv = 8 * ti - 3 + a, gu = 8 * tj - 3 + b;
        float val = 0.f;
        if ((unsigned)gv < 128u && (unsigned)gu < 128u) {
            const float* wp = c1w + c * 9;
            float bias = c1b[c];
            float s00 = bias, s01 = bias, s10 = bias, s11 = bias;
#pragma unroll
            for (int ky = 0; ky < 3; ky++) {
#pragma unroll
                for (int kx = 0; kx < 3; kx++) {
                    float wv = wp[ky * 3 + kx];
                    s00 += xl[2 * a + 0 + ky][2 * b + 0 + kx] * wv;
                    s01 += xl[2 * a + 0 + ky][2 * b + 1 + kx] * wv;
                    s10 += xl[2 * a + 1 + ky][2 * b + 0 + kx] * wv;
                    s11 += xl[2 * a + 1 + ky][2 * b + 1 + kx] * wv;
                }
            }
            val = fmaxf(fmaxf(fmaxf(s00, s01), fmaxf(s10, s11)), 0.f);
        }
        c1l[c][a][b] = val;
    }
    __syncthreads();

    for (int e = tid; e < 576; e += 256) {
        int c = e / 36, r = e - c * 36;
        int a = r / 6, b = r - a * 6;
        int gsy = 4 * ti - 1 + a, gsx = 4 * tj - 1 + b;
        float val = 0.f;
        if ((unsigned)gsy < 64u && (unsigned)gsx < 64u) {
            float bias = c2b[c];
            float s00 = bias, s01 = bias, s10 = bias, s11 = bias;
            const float* wb = c2w + c * 72;
#pragma unroll
            for (int ic = 0; ic < 8; ic++) {
                const float* wp = wb + ic * 9;
#pragma unroll
                for (int ky = 0; ky < 3; ky++) {
#pragma unroll
                    for (int kx = 0; kx < 3; kx++) {
                        float wv = wp[ky * 3 + kx];
                        s00 += c1l[ic][2 * a + 0 + ky][2 * b + 0 + kx] * wv;
                        s01 += c1l[ic][2 * a + 0 + ky][2 * b + 1 + kx] * wv;
                        s10 += c1l[ic][2 * a + 1 + ky][2 * b + 0 + kx] * wv;
                        s11 += c1l[ic][2 * a + 1 + ky][2 * b + 1 + kx] * wv;
                    }
                }
            }
            val = fmaxf(fmaxf(fmaxf(s00, s01), fmaxf(s10, s11)), 0.f);
        }
        c2l[c][a][b] = val;
    }
    __syncthreads();

    if (tid < 128) {
        int oc = tid >> 2, ql = tid & 3;
        int qly = ql >> 1, qlx = ql & 1;
        float bias = c3b[oc];
        float s00 = bias, s01 = bias, s10 = bias, s11 = bias;
        const float* wb = c3w + oc * 144;
#pragma unroll
        for (int ic = 0; ic < 16; ic++) {
            const float* wp = wb + ic * 9;
#pragma unroll
            for (int ky = 0; ky < 3; ky++) {
#pragma unroll
                for (int kx = 0; kx < 3; kx++) {
                    float wv = wp[ky * 3 + kx];
                    s00 += c2l[ic][2 * qly + 0 + ky][2 * qlx + 0 + kx] * wv;
                    s01 += c2l[ic][2 * qly + 0 + ky][2 * qlx + 1 + kx] * wv;
                    s10 += c2l[ic][2 * qly + 1 + ky][2 * qlx + 0 + kx] * wv;
                    s11 += c2l[ic][2 * qly + 1 + ky][2 * qlx + 1 + kx] * wv;
                }
            }
        }
        float val = fmaxf(fmaxf(fmaxf(s00, s01), fmaxf(s10, s11)), 0.f);
        NTS(&xconv[oc * 1024 + (2 * ti + qly) * 32 + (2 * tj + qlx)], val);
    }
}

// flat-segment split-K over w1 (r19)
__global__ void base_acc_k(const float* __restrict__ w1, const float* __restrict__ xconv,
                           float* __restrict__ base) {
    const size_t s0 = (size_t)blockIdx.x * BSEG;
    const int tid = threadIdx.x;
    int rowA = (int)(s0 / W1ROW);
    size_t rsA = (size_t)rowA * W1ROW;
    float accA = 0.f, accB = 0.f;
    bool fast = (s0 + BSEG <= rsA + 32768);
    if (fast) {
        int col0 = (int)(s0 - rsA);
        const float4* wp = (const float4*)(w1 + s0);
        const float2* xp = (const float2*)(xconv + col0);
#pragma unroll
        for (int p = 0; p < 2; p++) {
            int q = tid + p * 256;
            float4 a = wp[q];
            float2 v0 = xp[q * 2], v1 = xp[q * 2 + 1];
            accA += a.x * v0.x + a.y * v0.y + a.z * v1.x + a.w * v1.y;
        }
    } else {
#pragma unroll
        for (int p = 0; p < 2; p++) {
            size_t f = s0 + (size_t)(tid + p * 256) * 4;
#pragma unroll
            for (int e = 0; e < 4; e++) {
                size_t fe = f + e;
                if (fe < (size_t)TOTF) {
                    int r = (int)(fe / W1ROW);
                    int c = (int)(fe - (size_t)r * W1ROW);
                    if (c < 32768) {
                        float t = w1[fe] * xconv[c];
                        if (r == rowA) accA += t; else accB += t;
                    }
                }
            }
        }
    }
#pragma unroll
    for (int off = 32; off > 0; off >>= 1) {
        accA += __shfl_down(accA, off, 64);
        accB += __shfl_down(accB, off, 64);
    }
    __shared__ float redA[4], redB[4];
    int lane = tid & 63, wid = tid >> 6;
    if (lane == 0) { redA[wid] = accA; redB[wid] = accB; }
    __syncthreads();
    if (tid == 0) {
        atomicAdd(&base[rowA], redA[0] + redA[1] + redA[2] + redA[3]);
        float sB = redB[0] + redB[1] + redB[2] + redB[3];
        if (!fast && rowA + 1 < H1_ && sB != 0.f)
            atomicAdd(&base[rowA + 1], sB);
    }
}

// fused per-chunk MLP, 4 chunks per block, 1024 blocks (r3-proven optimum)
__global__ void chunk_k(const float* __restrict__ x, const float* __restrict__ base,
                        const float* __restrict__ w1pcT, const float* __restrict__ w2q,
                        const float* __restrict__ b2, const float* __restrict__ w3q,
                        const float* __restrict__ b3, float* __restrict__ out) {
    __shared__ float pc[CPB][18];
    __shared__ float h1[CPB][H1_];
    __shared__ float h2s[CPB][H2_];
    int tid = threadIdx.x;
    int c0 = blockIdx.x * CPB;

    if (tid < CPB * 18) {
        int u = tid / 18, k = tid - u * 18;
        int c = c0 + u;
        int i = c >> 6, j = c & 63;
        float v;
        if (k == 0)      v = (float)(i * 4);
        else if (k == 1) v = (float)(j * 4);
        else {
            int kk = k - 2;
            int r = kk >> 2, cc = kk & 3;
            v = x[(i * 4 + r) * 256 + j * 4 + cc];
        }
        pc[u][k] = v;
    }
    __syncthreads();

    // h1: 304 outputs x 4 chunks
    for (int t = tid; t < H1_; t += 256) {
        float bb = base[t];
        float acc[CPB];
#pragma unroll
        for (int u = 0; u < CPB; u++) acc[u] = bb;
#pragma unroll
        for (int k = 0; k < 18; k++) {
            float w = w1pcT[k * H1_ + t];
#pragma unroll
            for (int u = 0; u < CPB; u++) acc[u] += w * pc[u][k];
        }
#pragma unroll
        for (int u = 0; u < CPB; u++) h1[u][t] = fmaxf(acc[u], 0.f);
    }
    __syncthreads();

    // h2: 176 outputs x 4 chunks; w2q float4 coalesced, h1 broadcast reads
    if (tid < H2_) {
        const float4* wq = (const float4*)w2q;   // [76][176] float4s
        float acc[CPB];
#pragma unroll
        for (int u = 0; u < CPB; u++) acc[u] = b2[tid];
#pragma unroll 4
        for (int g = 0; g < 76; g++) {
            float4 w = wq[g * H2_ + tid];
#pragma unroll
            for (int u = 0; u < CPB; u++) {
                float4 h = *(const float4*)&h1[u][g * 4];
                acc[u] += w.x * h.x + w.y * h.y + w.z * h.z + w.w * h.w;
            }
        }
#pragma unroll
        for (int u = 0; u < CPB; u++) h2s[u][tid] = fmaxf(acc[u], 0.f);
    }
    __syncthreads();

    // out: 48 outputs x 4 chunks = 192 threads
    if (tid < CPB * OUT_) {
        int u = tid / OUT_, t = tid - u * OUT_;
        const float4* wq = (const float4*)w3q;   // [44][48] float4s
        float acc = b3[t];
#pragma unroll 4
        for (int g = 0; g < 44; g++) {
            float4 w = wq[g * OUT_ + t];
            float4 h = *(const float4*)&h2s[u][g * 4];
            acc += w.x * h.x + w.y * h.y + w.z * h.z + w.w * h.w;
        }
        out[(size_t)(c0 + u) * OUT_ + t] = 1.f / (1.f + expf(-acc));
    }
}

extern "C" void kernel_launch(void* const* d_in, const int* in_sizes, int n_in,
                              void* d_out, int out_size, void* d_ws, size_t ws_size,
                              hipStream_t stream) {
    const float* x    = (const float*)d_in[0];
    const float* c1_w = (const float*)d_in[1];
    const float* c1_b = (const float*)d_in[2];
    const float* c2_w = (const float*)d_in[3];
    const float* c2_b = (const float*)d_in[4];
    const float* c3_w = (const float*)d_in[5];
    const float* c3_b = (const float*)d_in[6];
    const float* w1   = (const float*)d_in[7];
    const float* b1   = (const float*)d_in[8];
    const float* w2   = (const float*)d_in[9];
    const float* b2   = (const float*)d_in[10];
    const float* w3   = (const float*)d_in[11];
    const float* b3   = (const float*)d_in[12];
    float* out = (float*)d_out;
    float* ws  = (float*)d_ws;

    float* xconv  = ws + WS_XC;
    float* base   = ws + WS_BASE;
    float* w1pcT  = ws + WS_W1PCT;
    float* w2q    = ws + WS_W2Q;
    float* w3q    = ws + WS_W3Q;

    fused_conv_prep_k<<<256 + 209, 256, 0, stream>>>(
        x, c1_w, c1_b, c2_w, c2_b, c3_w, c3_b, w1, w2, w3, b1,
        xconv, w1pcT, w2q, w3q, base);
    base_acc_k<<<NSEGB, 256, 0, stream>>>(w1, xconv, base);
    chunk_k<<<1024, 256, 0, stream>>>(x, base, w1pcT, w2q, b2, w3q, b3, out);
}